// Round 1
// baseline (225.521 us; speedup 1.0000x reference)
//
#include <hip/hip_runtime.h>

typedef __attribute__((ext_vector_type(8))) short bf16x8;
typedef __attribute__((ext_vector_type(4))) float f32x4;

#define E_DIM 100
#define L_SEQ 20
#define NV    30000
#define NVP   30080
#define MROWS 2000
#define MPAD  2048
#define KP    128

__device__ inline float sigmoidf_(float x){ return 1.f/(1.f+expf(-x)); }
__device__ inline unsigned short f2bf(float f){
  unsigned int u = __float_as_uint(f);
  return (unsigned short)((u + 0x7fffu + ((u>>16)&1u)) >> 16);
}

// ---------------- A: LSTM over the session, hu[b][t][e] ----------------
__global__ __launch_bounds__(512,2) void lstm_kernel(
    const int* __restrict__ seq, const float* __restrict__ item,
    const float* __restrict__ W_ih, const float* __restrict__ W_hh,
    const float* __restrict__ b_ih, const float* __restrict__ b_hh,
    float* __restrict__ hu){
  int b = blockIdx.x, j = threadIdx.x;
  __shared__ float4 xs4[25];
  __shared__ float4 hs4[25];
  __shared__ float gsh[400];
  float* xs = (float*)xs4; float* hs = (float*)hs4;
  float4 wih[25], whh[25];
  float bias = 0.f;
  if (j < 400){
    const float4* wi = (const float4*)(W_ih + j*E_DIM);
    const float4* wh = (const float4*)(W_hh + j*E_DIM);
#pragma unroll
    for (int k=0;k<25;k++) wih[k]=wi[k];
#pragma unroll
    for (int k=0;k<25;k++) whh[k]=wh[k];
    bias = b_ih[j] + b_hh[j];
  }
  if (j < 100) hs[j] = 0.f;
  float c = 0.f;
  for (int t=0;t<L_SEQ;t++){
    if (j < 100) xs[j] = item[(size_t)seq[b*L_SEQ+t]*E_DIM + j];
    __syncthreads();                      // hs(t-1) written, xs(t) ready
    if (j < 400){
      float acc = bias;
#pragma unroll
      for (int k=0;k<25;k++){ float4 x=xs4[k]; float4 w=wih[k]; acc += w.x*x.x+w.y*x.y+w.z*x.z+w.w*x.w; }
#pragma unroll
      for (int k=0;k<25;k++){ float4 h=hs4[k]; float4 w=whh[k]; acc += w.x*h.x+w.y*h.y+w.z*h.z+w.w*h.w; }
      gsh[j] = acc;
    }
    __syncthreads();                      // gates done, hs reads done
    if (j < 100){
      float ig=sigmoidf_(gsh[j]), fg=sigmoidf_(gsh[j+100]);
      float gg=tanhf(gsh[j+200]), og=sigmoidf_(gsh[j+300]);
      c = fg*c + ig*gg;
      float h = og*tanhf(c);
      hs[j] = h;
      hu[(size_t)(b*L_SEQ+t)*E_DIM + j] = h;
    }
  }
}

// ---------------- B: st2 (first-token LSTM step) + ls2 ----------------
__global__ void stageb_kernel(
    const int* __restrict__ ss2, const int* __restrict__ sn2,
    const float* __restrict__ item, const float* __restrict__ user,
    const float* __restrict__ W_ih, const float* __restrict__ b_ih, const float* __restrict__ b_hh,
    const float* __restrict__ W1, float* __restrict__ ls2){
  int n = blockIdx.x, j = threadIdx.x;
  __shared__ float4 xs4[25];  float* xs  = (float*)xs4;
  __shared__ float4 cat4[50]; float* cat = (float*)cat4;
  if (j < 100){
    xs[j]  = item[(size_t)ss2[n*L_SEQ]*E_DIM + j];
    cat[j] = user[(size_t)sn2[n]*E_DIM + j];
  }
  __syncthreads();
  if (j < 100){
    float ai=b_ih[j]+b_hh[j], ag=b_ih[200+j]+b_hh[200+j], ao=b_ih[300+j]+b_hh[300+j];
    const float4* wi=(const float4*)(W_ih + (size_t)j*E_DIM);
    const float4* wg=(const float4*)(W_ih + (size_t)(200+j)*E_DIM);
    const float4* wo=(const float4*)(W_ih + (size_t)(300+j)*E_DIM);
#pragma unroll
    for (int k=0;k<25;k++){
      float4 x=xs4[k];
      float4 a=wi[k]; ai += a.x*x.x+a.y*x.y+a.z*x.z+a.w*x.w;
      float4 g=wg[k]; ag += g.x*x.x+g.y*x.y+g.z*x.z+g.w*x.w;
      float4 o=wo[k]; ao += o.x*x.x+o.y*x.y+o.z*x.z+o.w*x.w;
    }
    float c0 = sigmoidf_(ai)*tanhf(ag);
    cat[100+j] = sigmoidf_(ao)*tanhf(c0);
  }
  __syncthreads();
  if (j < 100){
    float acc = 0.f;
    const float4* w1=(const float4*)(W1 + (size_t)j*200);
#pragma unroll
    for (int k=0;k<50;k++){ float4 cc=cat4[k]; float4 w=w1[k]; acc += w.x*cc.x+w.y*cc.y+w.z*cc.z+w.w*cc.w; }
    ls2[n*E_DIM + j] = fmaxf(acc, 0.f);
  }
}

// ---------------- C: GAT -> h0[b][e] ----------------
__global__ void gat_kernel(const float* __restrict__ hu, const float* __restrict__ ls2,
                           const float* __restrict__ Wg0, float* __restrict__ h0){
  int b = blockIdx.x, j = threadIdx.x; // 128 threads
  __shared__ float ns[6][100];
  __shared__ float wsc[6];
  __shared__ float ctx[100];
  if (j < 100) ns[5][j] = hu[(size_t)(b*L_SEQ)*E_DIM + j];
  for (int idx=j; idx<500; idx+=128){ int k=idx/100, e=idx-k*100; ns[k][e] = ls2[(b*5+k)*E_DIM + e]; }
  __syncthreads();
  if (j < 6){ float s=0.f; for (int e=0;e<100;e++) s += ns[5][e]*ns[j][e]; wsc[j]=s; }
  __syncthreads();
  if (j == 0){
    float m=wsc[0]; for (int k=1;k<6;k++) m=fmaxf(m,wsc[k]);
    float sum=0.f;
    for (int k=0;k<6;k++){ float e_=expf(wsc[k]-m); wsc[k]=e_; sum+=e_; }
    float inv=1.f/sum;
    for (int k=0;k<6;k++) wsc[k]*=inv;
  }
  __syncthreads();
  if (j < 100){ float cx=0.f; for (int k=0;k<6;k++) cx += wsc[k]*ns[k][j]; ctx[j]=cx; }
  __syncthreads();
  if (j < 100){
    float acc=0.f;
    for (int e=0;e<100;e++) acc += ctx[e]*Wg0[e*E_DIM + j];  // coalesced over j
    h0[b*E_DIM + j] = fmaxf(acc, 0.f);
  }
}

// ---------------- D: sr rows (m=b*20+l), f32 -> bf16, K padded to 128 ----------------
__global__ void sr_kernel(const float* __restrict__ hu, const float* __restrict__ h0,
                          const float* __restrict__ W2, unsigned short* __restrict__ srb){
  int m = blockIdx.x, j = threadIdx.x; // 128 threads
  if (m >= MROWS){ srb[(size_t)m*KP + j] = 0; return; }
  __shared__ float4 cat4[50]; float* cat=(float*)cat4;
  int b = m / L_SEQ;
  if (j < 100){ cat[j] = hu[(size_t)m*E_DIM + j]; cat[100+j] = h0[b*E_DIM + j]; }
  __syncthreads();
  float acc = 0.f;
  if (j < 100){
    const float4* w2=(const float4*)(W2 + (size_t)j*200);
#pragma unroll
    for (int k=0;k<50;k++){ float4 cc=cat4[k]; float4 w=w2[k]; acc += w.x*cc.x+w.y*cc.y+w.z*cc.z+w.w*cc.w; }
  }
  srb[(size_t)m*KP + j] = (j < 100) ? f2bf(acc) : (unsigned short)0;
}

// ---------------- P: item_emb f32 -> bf16, padded [30080][128] ----------------
__global__ void itemb_kernel(const float* __restrict__ item, unsigned short* __restrict__ ib){
  int t = blockIdx.x*256 + threadIdx.x;
  int v = t >> 6; int k = (t & 63) << 1;
  float a = 0.f, b2 = 0.f;
  if (v < NV && k < 100){ a = item[(size_t)v*E_DIM + k]; b2 = item[(size_t)v*E_DIM + k + 1]; }
  unsigned int pack = (unsigned int)f2bf(a) | ((unsigned int)f2bf(b2) << 16);
  *(unsigned int*)(ib + (size_t)v*KP + k) = pack;
}

// ---------------- E: logits = srb @ ib^T (bf16 MFMA, f32 acc), masked ----------------
__global__ __launch_bounds__(256) void gemm_kernel(
    const unsigned short* __restrict__ srb, const unsigned short* __restrict__ ib,
    const int* __restrict__ mask, float* __restrict__ out){
  __shared__ unsigned short As[128*KP];
  __shared__ unsigned short Bs[128*KP];
  int tile_n = blockIdx.x, tile_m = blockIdx.y;
  int tid = threadIdx.x;
  const float4* Ag = (const float4*)(srb + (size_t)tile_m*128*KP);
  const float4* Bg = (const float4*)(ib  + (size_t)tile_n*128*KP);
  float4* As4=(float4*)As; float4* Bs4=(float4*)Bs;
#pragma unroll
  for (int i=0;i<8;i++){
    int chunk = i*256 + tid;
    int row = chunk >> 4;
    int cb  = (chunk & 15) << 4;            // byte offset in row
    int sw  = cb ^ ((row & 7) << 4);        // XOR swizzle (G4: D=128 bf16 rows)
    int di  = row*16 + (sw >> 4);
    As4[di] = Ag[chunk];
    Bs4[di] = Bg[chunk];
  }
  __syncthreads();
  int wave = tid >> 6, lane = tid & 63;
  int wm = (wave >> 1) << 6, wn = (wave & 1) << 6;
  int lrow = lane & 15, lq = lane >> 4;
  f32x4 acc[4][4];
#pragma unroll
  for (int i=0;i<4;i++)
#pragma unroll
    for (int jj=0;jj<4;jj++) acc[i][jj] = (f32x4){0.f,0.f,0.f,0.f};
#pragma unroll
  for (int kk=0;kk<4;kk++){
    int koffb = (kk*32 + lq*8) * 2;         // byte offset along K
    bf16x8 a[4], bfr[4];
#pragma unroll
    for (int i=0;i<4;i++){
      int row = wm + i*16 + lrow;
      int boff = koffb ^ ((row & 7) << 4);
      a[i] = *(const bf16x8*)(As + row*KP + (boff >> 1));
    }
#pragma unroll
    for (int jj=0;jj<4;jj++){
      int row = wn + jj*16 + lrow;
      int boff = koffb ^ ((row & 7) << 4);
      bfr[jj] = *(const bf16x8*)(Bs + row*KP + (boff >> 1));
    }
#pragma unroll
    for (int i=0;i<4;i++)
#pragma unroll
      for (int jj=0;jj<4;jj++)
        acc[i][jj] = __builtin_amdgcn_mfma_f32_16x16x32_bf16(a[i], bfr[jj], acc[i][jj], 0, 0, 0);
  }
  // epilogue: C/D layout col=lane&15, row=(lane>>4)*4+reg  [m89]
  int v0 = tile_n*128 + wn;
  int m0 = tile_m*128 + wm;
#pragma unroll
  for (int i=0;i<4;i++){
    int mbase = m0 + i*16 + lq*4;
#pragma unroll
    for (int jj=0;jj<4;jj++){
      int v = v0 + jj*16 + lrow;
      if (v < NV){
#pragma unroll
        for (int r=0;r<4;r++){
          int m = mbase + r;
          if (m < MROWS)
            out[(size_t)m*NV + v] = acc[i][jj][r] * (float)mask[m];
        }
      }
    }
  }
}

extern "C" void kernel_launch(void* const* d_in, const int* in_sizes, int n_in,
                              void* d_out, int out_size, void* d_ws, size_t ws_size,
                              hipStream_t stream) {
  const int*   seq  = (const int*)d_in[0];
  const int*   sn2  = (const int*)d_in[2];
  const int*   ss2  = (const int*)d_in[4];
  const int*   mask = (const int*)d_in[5];
  const float* user = (const float*)d_in[6];
  const float* item = (const float*)d_in[7];
  const float* W_ih = (const float*)d_in[8];
  const float* W_hh = (const float*)d_in[9];
  const float* b_ih = (const float*)d_in[10];
  const float* b_hh = (const float*)d_in[11];
  const float* W1   = (const float*)d_in[12];
  const float* W2   = (const float*)d_in[13];
  const float* Wg0  = (const float*)d_in[14];
  float* out = (float*)d_out;
  char* ws = (char*)d_ws;

  float* hu  = (float*)(ws + 0);          //  800000 B
  float* h0  = (float*)(ws + 800000);     //   40000 B
  float* ls2 = (float*)(ws + 840000);     //  200000 B
  unsigned short* srb = (unsigned short*)(ws + 1048576);  // 2048*128*2 = 524288 B
  unsigned short* ib  = (unsigned short*)(ws + 2097152);  // 30080*128*2 = 7700480 B

  lstm_kernel<<<dim3(100), dim3(512), 0, stream>>>(seq, item, W_ih, W_hh, b_ih, b_hh, hu);
  stageb_kernel<<<dim3(500), dim3(128), 0, stream>>>(ss2, sn2, item, user, W_ih, b_ih, b_hh, W1, ls2);
  itemb_kernel<<<dim3(7520), dim3(256), 0, stream>>>(item, ib);
  gat_kernel<<<dim3(100), dim3(128), 0, stream>>>(hu, ls2, Wg0, h0);
  sr_kernel<<<dim3(MPAD), dim3(128), 0, stream>>>(hu, h0, W2, srb);
  gemm_kernel<<<dim3(235, 16), dim3(256), 0, stream>>>(srb, ib, mask, out);
}